// Round 17
// baseline (1232.279 us; speedup 1.0000x reference)
//
#include <hip/hip_runtime.h>
#include <stdint.h>

typedef unsigned short u16;
typedef __bf16 bf16x8 __attribute__((ext_vector_type(8)));
typedef float f32x4 __attribute__((ext_vector_type(4)));

#define BDIM 16
#define SLEN 512
#define DMODEL 1024
#define NHEAD 16
#define DHEAD 64
#define FDIM 4096
#define NLAYER 4
#define ROWS (BDIM*SLEN)   // 8192
#define KVT 64             // keys per attention tile
#define QBLK 128           // q-rows per attention block

// f32 -> bf16 round-to-nearest-even
__device__ __forceinline__ u16 f2b(float f) {
  uint32_t u = __builtin_bit_cast(uint32_t, f);
  u = (u + 0x7fffu + ((u >> 16) & 1u)) >> 16;
  return (u16)u;
}
__device__ __forceinline__ float b2f(u16 u) {
  return __builtin_bit_cast(float, (uint32_t)u << 16);
}
__device__ __forceinline__ float b2f_lo(uint32_t u) {
  return __builtin_bit_cast(float, u << 16);
}
__device__ __forceinline__ float b2f_hi(uint32_t u) {
  return __builtin_bit_cast(float, u & 0xffff0000u);
}

// async global->LDS, 16B per lane. LDS dest is WAVE-UNIFORM base (+lane*16 by HW);
// global src is per-lane (how we realize swizzled LDS layouts).
__device__ __forceinline__ void gl_lds16(const void* g, void* l) {
  uint32_t loff = (uint32_t)(uintptr_t)l;
  __builtin_amdgcn_global_load_lds(
      (__attribute__((address_space(1))) uint32_t*)(uintptr_t)g,
      (__attribute__((address_space(3))) uint32_t*)loff,
      16, 0, 0);
}

// ---------------- prep: xb = bf16(q + pe), yb = bf16(qa + pe) ----------------
__global__ __launch_bounds__(256) void prep_kernel(const float4* __restrict__ q,
                                                   const float4* __restrict__ qa,
                                                   const float4* __restrict__ pe,
                                                   u16* __restrict__ xb,
                                                   u16* __restrict__ yb) {
  int idx = blockIdx.x * 256 + threadIdx.x;
  int pidx = idx & (SLEN * DMODEL / 4 - 1);
  float4 qv = q[idx], av = qa[idx], pv = pe[pidx];
  uint32_t x0 = (uint32_t)f2b(qv.x + pv.x) | ((uint32_t)f2b(qv.y + pv.y) << 16);
  uint32_t x1 = (uint32_t)f2b(qv.z + pv.z) | ((uint32_t)f2b(qv.w + pv.w) << 16);
  uint32_t y0 = (uint32_t)f2b(av.x + pv.x) | ((uint32_t)f2b(av.y + pv.y) << 16);
  uint32_t y1 = (uint32_t)f2b(av.z + pv.z) | ((uint32_t)f2b(av.w + pv.w) << 16);
  ((uint2*)xb)[idx] = make_uint2(x0, x1);
  ((uint2*)yb)[idx] = make_uint2(y0, y1);
}

// ---------------- transpose f32 [M][N] -> bf16 [N][M], layer z ----------------
__global__ __launch_bounds__(256) void transpose_f2b(const float* __restrict__ in,
                                                     u16* __restrict__ out,
                                                     int M, int N) {
  __shared__ float t[32][33];
  int tx = threadIdx.x & 31, ty = threadIdx.x >> 5;
  int m0 = blockIdx.y * 32, n0 = blockIdx.x * 32;
  const float* inz = in + (size_t)blockIdx.z * M * N;
  u16* outz = out + (size_t)blockIdx.z * M * N;
  #pragma unroll
  for (int i = 0; i < 32; i += 8) t[ty + i][tx] = inz[(size_t)(m0 + ty + i) * N + n0 + tx];
  __syncthreads();
  #pragma unroll
  for (int i = 0; i < 32; i += 8) outz[(size_t)(n0 + ty + i) * M + m0 + tx] = f2b(t[tx][ty + i]);
}

// ---------------- 8-phase 256x256 GEMM (FFN1; proven config — swizzle kept as CONTROL) ----------------
template<int BN, bool RELU, bool BF16OUT>
__global__ __launch_bounds__(512, 2) void gemm8p(const u16* __restrict__ Ap,
                                                 const u16* __restrict__ Bp,
                                                 const float* __restrict__ bias,
                                                 void* __restrict__ Cp,
                                                 int M, int N, int K) {
  constexpr int NBH = BN / 128;
  constexpr int NREP = BN / 64;
  constexpr int QN = NREP / 2;
  constexpr int HU = 8192;
  __shared__ __attribute__((aligned(16))) u16 lds[2][(2 + NBH) * HU];

  const int tid = threadIdx.x, wave = tid >> 6, lane = tid & 63;
  const int lg = lane >> 4, lc = lane & 15;
  const int wm = wave >> 2, wn = wave & 3;

  const int gx = gridDim.x;
  int nwg = gx * gridDim.y;
  int orig = blockIdx.y * gx + blockIdx.x;
  int qq = nwg >> 3, rr_ = nwg & 7;
  int xcd = orig & 7, ix = orig >> 3;
  int wg = (xcd < rr_ ? xcd * (qq + 1) : rr_ * (qq + 1) + (xcd - rr_) * qq) + ix;
  const int m0 = (wg / gx) * 256, n0 = (wg % gx) * BN;

  const int ldbyte = K * 2;
  const char* Ag = (const char*)Ap + (size_t)m0 * ldbyte;
  const char* Bg = (const char*)Bp + (size_t)n0 * ldbyte;

  int o1 = tid * 16, o2 = 8192 + tid * 16;
  int sr1 = o1 >> 7, sg1 = (((o1 >> 4) & 7) - sr1) & 7;
  int sr2 = o2 >> 7, sg2 = (((o2 >> 4) & 7) - sr2) & 7;
  const int soff1 = sr1 * ldbyte + sg1 * 16;
  const int soff2 = sr2 * ldbyte + sg2 * 16;
  const int NT = K >> 6;

  auto stageA = [&](int kt, int h, int buf) {
    const char* g = Ag + (size_t)h * 128 * ldbyte + (size_t)kt * 128;
    char* d = (char*)&lds[buf][h * HU] + wave * 1024;
    gl_lds16(g + soff1, d);
    gl_lds16(g + soff2, d + 8192);
  };
  auto stageB = [&](int kt, int h, int buf) {
    const char* g = Bg + (size_t)h * 128 * ldbyte + (size_t)kt * 128;
    char* d = (char*)&lds[buf][(2 + h) * HU] + wave * 1024;
    gl_lds16(g + soff1, d);
    gl_lds16(g + soff2, d + 8192);
  };

  const int bstart = wn * (BN / 4);
  const int bh = bstart >> 7, bc0 = bstart & 127;

  auto rdA = [&](const u16* base, int f, int kk) -> bf16x8 {
    int row = f * 16 + lc;
    return *(const bf16x8*)&base[row * 64 + (((kk * 4 + lg + row) & 7) << 3)];
  };
  auto rdB = [&](const u16* base, int jj, int kk) -> bf16x8 {
    int row = bc0 + jj * 16 + lc;
    return *(const bf16x8*)&base[row * 64 + (((kk * 4 + lg + row) & 7) << 3)];
  };

  f32x4 acc[8][NREP];
  #pragma unroll
  for (int f = 0; f < 8; f++)
    #pragma unroll
    for (int j = 0; j < NREP; j++) acc[f][j] = (f32x4){0.f, 0.f, 0.f, 0.f};

  stageA(0, 0, 0); stageA(0, 1, 0);
  stageB(0, 0, 0); if (NBH == 2) stageB(0, 1, 0);
  stageA(1, 0, 1); stageA(1, 1, 1);
  asm volatile("s_waitcnt vmcnt(4)\n\ts_barrier" ::: "memory");

  auto ktile = [&](int k, int buf) {
    const u16* Ab_ = &lds[buf][wm * HU];
    const u16* Bb_ = &lds[buf][(2 + bh) * HU];
    const int kn = (k + 1 < NT) ? k + 1 : NT - 1;
    const int k2 = (k + 2 < NT) ? k + 2 : NT - 1;
    bf16x8 a0[4][2], a1[4][2], b0[QN][2], b1[QN][2];

    #pragma unroll
    for (int f = 0; f < 4; f++) { a0[f][0] = rdA(Ab_, f, 0); a0[f][1] = rdA(Ab_, f, 1); }
    #pragma unroll
    for (int j = 0; j < QN; j++) { b0[j][0] = rdB(Bb_, j, 0); b0[j][1] = rdB(Bb_, j, 1); }
    stageB(kn, 0, buf ^ 1);
    asm volatile("s_barrier" ::: "memory");
    __builtin_amdgcn_s_setprio(1);
    #pragma unroll
    for (int f = 0; f < 4; f++)
      #pragma unroll
      for (int j = 0; j < QN; j++) {
        acc[f][j] = __builtin_amdgcn_mfma_f32_16x16x32_bf16(a0[f][0], b0[j][0], acc[f][j], 0, 0, 0);
        acc[f][j] = __builtin_amdgcn_mfma_f32_16x16x32_bf16(a0[f][1], b0[j][1], acc[f][j], 0, 0, 0);
      }
    __builtin_amdgcn_s_setprio(0);
    asm volatile("s_barrier" ::: "memory");

    #pragma unroll
    for (int f = 0; f < 4; f++) { a1[f][0] = rdA(Ab_, 4 + f, 0); a1[f][1] = rdA(Ab_, 4 + f, 1); }
    if (NBH == 2) stageB(kn, 1, buf ^ 1);
    asm volatile("s_barrier" ::: "memory");
    __builtin_amdgcn_s_setprio(1);
    #pragma unroll
    for (int f = 0; f < 4; f++)
      #pragma unroll
      for (int j = 0; j < QN; j++) {
        acc[4 + f][j] = __builtin_amdgcn_mfma_f32_16x16x32_bf16(a1[f][0], b0[j][0], acc[4 + f][j], 0, 0, 0);
        acc[4 + f][j] = __builtin_amdgcn_mfma_f32_16x16x32_bf16(a1[f][1], b0[j][1], acc[4 + f][j], 0, 0, 0);
      }
    __builtin_amdgcn_s_setprio(0);
    asm volatile("s_barrier" ::: "memory");

    #pragma unroll
    for (int j = 0; j < QN; j++) { b1[j][0] = rdB(Bb_, QN + j, 0); b1[j][1] = rdB(Bb_, QN + j, 1); }
    stageA(k2, 0, buf);
    asm volatile("s_barrier" ::: "memory");
    __builtin_amdgcn_s_setprio(1);
    #pragma unroll
    for (int f = 0; f < 4; f++)
      #pragma unroll
      for (int j = 0; j < QN; j++) {
        acc[4 + f][QN + j] = __builtin_amdgcn_mfma_f32_16x16x32_bf16(a1[f][0], b1[j][0], acc[4 + f][QN + j], 0, 0, 0);
        acc[4 + f][QN + j] = __builtin_amdgcn_mfma_f32_16x16x32_bf16(a1[f][1], b1[j][1], acc[4 + f][QN + j], 0, 0, 0);
      }
    __builtin_amdgcn_s_setprio(0);
    asm volatile("s_barrier" ::: "memory");

    stageA(k2, 1, buf);
    asm volatile("s_barrier" ::: "memory");
    __builtin_amdgcn_s_setprio(1);
    #pragma unroll
    for (int f = 0; f < 4; f++)
      #pragma unroll
      for (int j = 0; j < QN; j++) {
        acc[f][QN + j] = __builtin_amdgcn_mfma_f32_16x16x32_bf16(a0[f][0], b1[j][0], acc[f][QN + j], 0, 0, 0);
        acc[f][QN + j] = __builtin_amdgcn_mfma_f32_16x16x32_bf16(a0[f][1], b1[j][1], acc[f][QN + j], 0, 0, 0);
      }
    __builtin_amdgcn_s_setprio(0);
    asm volatile("s_waitcnt vmcnt(4)\n\ts_barrier" ::: "memory");
  };

  for (int k = 0; k < NT; k += 2) {
    ktile(k, 0);
    ktile(k + 1, 1);
  }

  #pragma unroll
  for (int f = 0; f < 8; f++) {
    int row = m0 + wm * 128 + f * 16 + lg * 4;
    #pragma unroll
    for (int j = 0; j < NREP; j++) {
      int col = n0 + bstart + j * 16 + lc;
      float bv = bias[col];
      #pragma unroll
      for (int t2 = 0; t2 < 4; t2++) {
        float v = acc[f][j][t2] + bv;
        if (RELU) v = fmaxf(v, 0.f);
        if (BF16OUT) ((u16*)Cp)[(size_t)(row + t2) * N + col] = f2b(v);
        else         ((float*)Cp)[(size_t)(row + t2) * N + col] = v;
      }
    }
  }
}

// ---------------- gemm4w v1: 128x128, BK=64, race-hardened — NO XCD swizzle (L3-fit regime) ----------------
// Identity tile mapping: HW round-robin puts all blocks with the same n-panel (bx) on one XCD,
// making the 1MB B-slice L2-resident; A-panels stream through L3 once (m160: swizzle costs when L3-fit).
template<bool RESID, bool DUAL>
__global__ __launch_bounds__(256, 2) void gemm4w(const u16* __restrict__ Ap,
                                                 const u16* __restrict__ Bp,
                                                 const float* __restrict__ bias,
                                                 const u16* __restrict__ Rp,
                                                 u16* __restrict__ Cp,
                                                 const u16* __restrict__ Ap2,
                                                 const u16* __restrict__ Bp2,
                                                 const float* __restrict__ bias2,
                                                 u16* __restrict__ Cp2,
                                                 int M, int N, int K) {
  __shared__ __attribute__((aligned(16))) u16 As[2][128 * 64];
  __shared__ __attribute__((aligned(16))) u16 Bs[2][128 * 64];
  const int tid = threadIdx.x, wave = tid >> 6, lane = tid & 63;
  const int lg = lane >> 4, lc = lane & 15;
  const int wm = wave >> 1, wn = wave & 1;

  if (DUAL && blockIdx.z == 1) { Ap = Ap2; Bp = Bp2; bias = bias2; Cp = Cp2; }

  const int m0 = blockIdx.y * 128, n0 = blockIdx.x * 128;   // identity mapping

  const int ldbyte = K * 2;
  const char* Ag = (const char*)Ap + (size_t)m0 * ldbyte;
  const char* Bg = (const char*)Bp + (size_t)n0 * ldbyte;
  const int NT = K >> 6;

  auto stage = [&](const char* gb, int kt, u16* lb) {
    #pragma unroll
    for (int c = 0; c < 4; c++) {
      int o = c * 4096 + tid * 16;
      int row = o >> 7;
      int g = (((o >> 4) & 7) - row) & 7;
      gl_lds16(gb + (size_t)row * ldbyte + (size_t)kt * 128 + g * 16,
               (char*)lb + c * 4096 + wave * 1024);
    }
  };
  auto rd = [&](const u16* base, int strip, int f, int kk) -> bf16x8 {
    int row = strip * 64 + f * 16 + lc;
    return *(const bf16x8*)&base[row * 64 + (((kk * 4 + lg + row) & 7) << 3)];
  };

  f32x4 acc[4][4];
  #pragma unroll
  for (int f = 0; f < 4; f++)
    #pragma unroll
    for (int n = 0; n < 4; n++) acc[f][n] = (f32x4){0.f, 0.f, 0.f, 0.f};

  stage(Ag, 0, As[0]); stage(Bg, 0, Bs[0]);
  stage(Ag, 1, As[1]); stage(Bg, 1, Bs[1]);
  asm volatile("s_waitcnt vmcnt(8)\n\ts_barrier" ::: "memory");

  for (int k = 0; k < NT; k++) {
    const int buf = k & 1;
    const int k2 = (k + 2 < NT) ? k + 2 : k;   // same-parity clamp: restage = identical bytes
    bf16x8 a[4][2], b[4][2];
    #pragma unroll
    for (int f = 0; f < 4; f++) { a[f][0] = rd(As[buf], wm, f, 0); a[f][1] = rd(As[buf], wm, f, 1); }
    #pragma unroll
    for (int n = 0; n < 4; n++) { b[n][0] = rd(Bs[buf], wn, n, 0); b[n][1] = rd(Bs[buf], wn, n, 1); }
    asm volatile("s_barrier" ::: "memory");              // B1
    __builtin_amdgcn_s_setprio(1);
    #pragma unroll
    for (int f = 0; f < 4; f++)
      #pragma unroll
      for (int n = 0; n < 2; n++) {
        acc[f][n] = __builtin_amdgcn_mfma_f32_16x16x32_bf16(a[f][0], b[n][0], acc[f][n], 0, 0, 0);
        acc[f][n] = __builtin_amdgcn_mfma_f32_16x16x32_bf16(a[f][1], b[n][1], acc[f][n], 0, 0, 0);
      }
    __builtin_amdgcn_s_setprio(0);
    asm volatile("s_waitcnt lgkmcnt(0)\n\ts_barrier" ::: "memory");  // B2: all LDS reads drained
    stage(Ag, k2, As[buf]);
    stage(Bg, k2, Bs[buf]);
    __builtin_amdgcn_s_setprio(1);
    #pragma unroll
    for (int f = 0; f < 4; f++)
      #pragma unroll
      for (int n = 2; n < 4; n++) {
        acc[f][n] = __builtin_amdgcn_mfma_f32_16x16x32_bf16(a[f][0], b[n][0], acc[f][n], 0, 0, 0);
        acc[f][n] = __builtin_amdgcn_mfma_f32_16x16x32_bf16(a[f][1], b[n][1], acc[f][n], 0, 0, 0);
      }
    __builtin_amdgcn_s_setprio(0);
    asm volatile("s_waitcnt vmcnt(8)\n\ts_barrier" ::: "memory");  // B3: tile k+1 landed
  }

  #pragma unroll
  for (int f = 0; f < 4; f++) {
    int row = m0 + wm * 64 + f * 16 + lg * 4;
    #pragma unroll
    for (int n = 0; n < 4; n++) {
      int col = n0 + wn * 64 + n * 16 + lc;
      float bv = bias[col];
      #pragma unroll
      for (int r = 0; r < 4; r++) {
        float v = acc[f][n][r] + bv;
        if (RESID) v += b2f(Rp[(size_t)(row + r) * N + col]);
        Cp[(size_t)(row + r) * N + col] = f2b(v);
      }
    }
  }
}

// ---------------- flash attention v7: QBLK=128, KVT=64, hardened sync, static-max softmax ----------------
__global__ __launch_bounds__(256, 2) void attn_kernel(const u16* __restrict__ QK,
                                                      const u16* __restrict__ V,
                                                      u16* __restrict__ CTX) {
  __shared__ __attribute__((aligned(16))) u16 Ks[2][KVT * 64];
  __shared__ __attribute__((aligned(16))) u16 VTs[64 * 72];
  __shared__ __attribute__((aligned(16))) u16 Ps[4][32 * 72];
  const int qt = blockIdx.x, bh = blockIdx.y;
  const int b = bh >> 4, h = bh & 15;
  const char* Qg = (const char*)(QK + (size_t)b * SLEN * DMODEL + h * DHEAD);
  const char* Vg = (const char*)(V + (size_t)b * SLEN * DMODEL + h * DHEAD);
  const int tid = threadIdx.x, wave = tid >> 6, lane = tid & 63;
  const int lg = lane >> 4, lc = lane & 15;
  const int ktmax = (qt * QBLK + QBLK - 2) >> 6;   // = 2*qt+1 (odd -> even iteration count)

  auto stageK = [&](int kt, int buf) {
    #pragma unroll
    for (int i = 0; i < 2; i++) {
      int o = i * 4096 + tid * 16;
      int row = o >> 7, slot = (o >> 4) & 7;
      int g = (slot - row) & 7;
      gl_lds16(Qg + (size_t)(kt * KVT + row) * (DMODEL * 2) + g * 16,
               (char*)Ks[buf] + i * 4096 + wave * 1024);
    }
  };
  const int vhi = lane >> 5, vls = lane & 31;
  const int vc_ = wave + 4 * vhi;
  auto loadV = [&](int kt, uint4 (&va)[2]) {
    const char* src = Vg + (size_t)(kt * KVT + 2 * vls) * (DMODEL * 2) + vc_ * 16;
    va[0] = *(const uint4*)src;
    va[1] = *(const uint4*)(src + DMODEL * 2);
  };
  auto writeVT = [&](const uint4 (&va)[2]) {
    u16 e0[8], e1[8];
    *(uint4*)e0 = va[0];
    *(uint4*)e1 = va[1];
    #pragma unroll
    for (int j = 0; j < 8; j++) {
      uint32_t pk = (uint32_t)e0[j] | ((uint32_t)e1[j] << 16);
      *(uint32_t*)&VTs[(8 * vc_ + j) * 72 + 2 * vls] = pk;
    }
  };

  uint4 vaA[2], vaB[2];
  bf16x8 aq[2][2];
  #pragma unroll
  for (int f = 0; f < 2; f++) {
    const int qrow = qt * QBLK + wave * 32 + f * 16 + lc;
    aq[f][0] = *(const bf16x8*)(Qg + (size_t)qrow * (DMODEL * 2) + lg * 16);
    aq[f][1] = *(const bf16x8*)(Qg + (size_t)qrow * (DMODEL * 2) + 64 + lg * 16);
  }
  stageK(0, 0);
  loadV(0, vaA);
  stageK(1, 1);
  asm volatile("s_waitcnt vmcnt(2)\n\ts_barrier" ::: "memory");

  float l_run[2][4] = {{0.f, 0.f, 0.f, 0.f}, {0.f, 0.f, 0.f, 0.f}};
  f32x4 acc_o[2][4];
  #pragma unroll
  for (int f = 0; f < 2; f++)
    #pragma unroll
    for (int n = 0; n < 4; n++) acc_o[f][n] = (f32x4){0.f, 0.f, 0.f, 0.f};

  auto iter = [&](int kt, int cur, uint4 (&vc)[2], uint4 (&vn)[2]) {
    const int kn = (kt + 1 <= ktmax) ? kt + 1 : ktmax;
    const int k2 = (kt + 2 <= ktmax) ? kt + 2 : kt;   // same-parity clamp (identical bytes)

    asm volatile("s_waitcnt vmcnt(2) lgkmcnt(0)" ::: "memory");
    __builtin_amdgcn_s_barrier();                     // B0: VT free for rewrite
    writeVT(vc);
    loadV(kn, vn);

    f32x4 sc[2][4];
    #pragma unroll
    for (int f = 0; f < 2; f++)
      #pragma unroll
      for (int n = 0; n < 4; n++) sc[f][n] = (f32x4){0.f, 0.f, 0.f, 0.f};
    #pragma unroll
    for (int n = 0; n < 4; n++) {
      int row = n * 16 + lc;
      bf16x8 bk0 = *(const bf16x8*)&Ks[cur][row * 64 + (((lg + row) & 7) << 3)];
      bf16x8 bk1 = *(const bf16x8*)&Ks[cur][row * 64 + (((4 + lg + row) & 7) << 3)];
      #pragma unroll
      for (int f = 0; f < 2; f++) {
        sc[f][n] = __builtin_amdgcn_mfma_f32_16x16x32_bf16(aq[f][0], bk0, sc[f][n], 0, 0, 0);
        sc[f][n] = __builtin_amdgcn_mfma_f32_16x16x32_bf16(aq[f][1], bk1, sc[f][n], 0, 0, 0);
      }
    }

    #pragma unroll
    for (int f = 0; f < 2; f++) {
      const int qbase = qt * QBLK + wave * 32 + f * 16 + lg * 4;
      #pragma unroll
      for (int n = 0; n < 4; n++) {
        int kg = kt * KVT + n * 16 + lc;
        #pragma unroll
        for (int r = 0; r < 4; r++) {
          float e = __expf(fmaf(sc[f][n][r], 0.125f, -24.f));
          float p = (kg < qbase + r) ? e : 0.f;
          l_run[f][r] += p;
          Ps[wave][(f * 16 + lg * 4 + r) * 72 + n * 16 + lc] = f2b(p);
        }
      }
    }

    asm volatile("s_waitcnt lgkmcnt(0)" ::: "memory");
    __builtin_amdgcn_s_barrier();            // B1: VT+P visible; QK reads of Ks[cur] done
    stageK(k2, cur);

    bf16x8 ap[2][2];
    #pragma unroll
    for (int f = 0; f < 2; f++) {
      ap[f][0] = *(const bf16x8*)&Ps[wave][(f * 16 + lc) * 72 + lg * 8];
      ap[f][1] = *(const bf16x8*)&Ps[wave][(f * 16 + lc) * 72 + 32 + lg * 8];
    }
    #pragma unroll
    for (int n2 = 0; n2 < 4; n2++) {
      bf16x8 bv0 = *(const bf16x8*)&VTs[(n2 * 16 + lc) * 72 + lg * 8];
      bf16x8 bv1 = *(const bf16x8*)&VTs[(n2 * 16 + lc) * 72 + 32 + lg * 8];
      #pragma unroll
      for (int f = 0; f < 2; f++) {
        acc_o[f][n2] = __builtin_amdgcn_mfma_f32_16x16x32_bf16(ap[f][0], bv0, acc_o[f][n2], 0, 0, 0);
        acc_o[f][n2] = __builtin_amdgcn_mfma_f32_16x16x32_bf16(ap[f][1], bv1, acc_o[f][n2], 0, 0, 0);
      }
    }
  };

  for (int kt = 0; kt <= ktmax; kt += 2) {
    iter(kt, 0, vaA, vaB);
    iter(kt + 1, 1, vaB, vaA);   // ktmax odd -> always valid
  }

  #pragma unroll
  for (int d = 1; d < 16; d <<= 1)
    #pragma unroll
    for (int f = 0; f < 2; f++)
      #pragma unroll
      for (int r = 0; r < 4; r++) l_run[f][r] += __shfl_xor(l_run[f][r], d, 64);

  asm volatile("s_waitcnt vmcnt(0)" ::: "memory");
  #pragma unroll
  for (int f = 0; f < 2; f++)
    #pragma unroll
    for (int n2 = 0; n2 < 4; n2++)
      #pragma unroll
      for (int r = 0; r < 4; r++) {
        int sq = qt * QBLK + wave * 32 + f * 16 + lg * 4 + r;
        float v = (sq == 0) ? 0.f : acc_o[f][n2][r] / l_run[f][r];
        CTX[((size_t)b * SLEN + sq) * DMODEL + h * DHEAD + n2 * 16 + lc] = f2b(v);
      }
}

// ---------------- pure row LayerNorm (bit-exact); OUT32 fuses the f32 expand ----------------
template<bool OUT32>
__global__ __launch_bounds__(256) void ln_kernel(const u16* __restrict__ tmp,
                                                 u16* __restrict__ xb,
                                                 const float* __restrict__ gw,
                                                 const float* __restrict__ bw,
                                                 float4* __restrict__ outf) {
  __shared__ float red[4], red2[4];
  const int row = blockIdx.x, t = threadIdx.x;
  const size_t base = (size_t)row * DMODEL + t * 4;
  uint2 tv = *(const uint2*)&tmp[base];
  float v[4];
  v[0] = b2f_lo(tv.x); v[1] = b2f_hi(tv.x);
  v[2] = b2f_lo(tv.y); v[3] = b2f_hi(tv.y);
  float s = v[0] + v[1] + v[2] + v[3];
  #pragma unroll
  for (int d = 1; d < 64; d <<= 1) s += __shfl_xor(s, d, 64);
  if ((t & 63) == 0) red[t >> 6] = s;
  __syncthreads();
  float mean = (red[0] + red[1] + red[2] + red[3]) * (1.f / DMODEL);
  float q2 = 0.f;
  #pragma unroll
  for (int i = 0; i < 4; i++) { float d_ = v[i] - mean; q2 += d_ * d_; }
  #pragma unroll
  for (int d = 1; d < 64; d <<= 1) q2 += __shfl_xor(q2, d, 64);
  if ((t & 63) == 0) red2[t >> 6] = q2;
  __syncthreads();
  float var = (red2[0] + red2[1] + red2[2] + red2[3]) * (1.f / DMODEL);
  float rs = rsqrtf(var + 1e-5f);
  float4 gv = *(const float4*)&gw[t * 4];
  float4 bv4 = *(const float4*)&bw[t * 4];
  float o0 = (v[0] - mean) * rs * gv.x + bv4.x;
  float o1 = (v[1] - mean) * rs * gv.y + bv4.y;
  float o2 = (v[2] - mean) * rs * gv.z + bv4.z;
  float o3 = (v[3] - mean) * rs * gv.w + bv4.w;
  if (OUT32) {
    outf[(size_t)row * (DMODEL / 4) + t] =
        make_float4(b2f(f2b(o0)), b2f(f2b(o1)), b2f(f2b(o2)), b2f(f2b(o3)));
  } else {
    uint2 pk;
    pk.x = (uint32_t)f2b(o0) | ((uint32_t)f2b(o1) << 16);
    pk.y = (uint32_t)f2b(o2) | ((uint32_t)f2b(o3) << 16);
    *(uint2*)&xb[base] = pk;
  }
}

extern "C" void kernel_launch(void* const* d_in, const int* in_sizes, int n_in,
                              void* d_out, int out_size, void* d_ws, size_t ws_size,
                              hipStream_t stream) {
  (void)in_sizes; (void)n_in; (void)out_size;
  const float* q    = (const float*)d_in[0];
  const float* qa   = (const float*)d_in[1];
  const float* pe   = (const float*)d_in[2];
  const float* Wk   = (const float*)d_in[3];
  const float* bk   = (const float*)d_in[4];
  const float* Wv   = (const float*)d_in[5];
  const float* bv   = (const float*)d_in[6];
  const float* Wo   = (const float*)d_in[7];
  const float* bo   = (const float*)d_in[8];
  const float* ln1g = (const float*)d_in[9];
  const float* ln1b = (const float*)d_in[10];
  const float* W1   = (const float*)d_in[11];
  const float* b1   = (const float*)d_in[12];
  const float* W2   = (const float*)d_in[13];
  const float* b2   = (const float*)d_in[14];
  const float* ln2g = (const float*)d_in[15];
  const float* ln2b = (const float*)d_in[16];

  char* w = (char*)d_ws;
  u16* xb   = (u16*)w; w += (size_t)ROWS * DMODEL * 2;
  u16* yb   = (u16*)w; w += (size_t)ROWS * DMODEL * 2;
  u16* qkb  = (u16*)w; w += (size_t)ROWS * DMODEL * 2;
  u16* vb   = (u16*)w; w += (size_t)ROWS * DMODEL * 2;
  u16* ctxb = (u16*)w; w += (size_t)ROWS * DMODEL * 2;
  u16* ffnb = (u16*)w; w += (size_t)ROWS * FDIM * 2;
  u16* tmpb = qkb;   // alias: qkb dead when tmpb written

  const size_t DD = (size_t)DMODEL * DMODEL, DF = (size_t)DMODEL * FDIM;
  size_t used = (size_t)(w - (char*)d_ws);
  const bool hoist = ws_size >= used + (3 * DD + 2 * DF) * NLAYER * 2;

  u16 *WkT, *WvT, *WoT, *W1T, *W2T;
  if (hoist) {
    WkT = (u16*)w; w += DD * NLAYER * 2;
    WvT = (u16*)w; w += DD * NLAYER * 2;
    WoT = (u16*)w; w += DD * NLAYER * 2;
    W1T = (u16*)w; w += DF * NLAYER * 2;
    W2T = (u16*)w; w += DF * NLAYER * 2;
  } else {
    WkT = (u16*)w; w += DD * 2;
    WvT = (u16*)w; w += DD * 2;
    WoT = (u16*)w; w += DD * 2;
    W1T = (u16*)w; w += DF * 2;
    W2T = (u16*)w; w += DF * 2;
  }

  prep_kernel<<<ROWS * DMODEL / 4 / 256, 256, 0, stream>>>(
      (const float4*)q, (const float4*)qa, (const float4*)pe, xb, yb);

  if (hoist) {
    transpose_f2b<<<dim3(32, 32, NLAYER), 256, 0, stream>>>(Wk, WkT, DMODEL, DMODEL);
    transpose_f2b<<<dim3(32, 32, NLAYER), 256, 0, stream>>>(Wv, WvT, DMODEL, DMODEL);
    transpose_f2b<<<dim3(32, 32, NLAYER), 256, 0, stream>>>(Wo, WoT, DMODEL, DMODEL);
    transpose_f2b<<<dim3(128, 32, NLAYER), 256, 0, stream>>>(W1, W1T, DMODEL, FDIM);
    transpose_f2b<<<dim3(32, 128, NLAYER), 256, 0, stream>>>(W2, W2T, FDIM, DMODEL);
  }

  for (int l = 0; l < NLAYER; l++) {
    u16 *WkTl, *WvTl, *WoTl, *W1Tl, *W2Tl;
    if (hoist) {
      WkTl = WkT + l * DD; WvTl = WvT + l * DD; WoTl = WoT + l * DD;
      W1Tl = W1T + l * DF; W2Tl = W2T + l * DF;
    } else {
      transpose_f2b<<<dim3(32, 32), 256, 0, stream>>>(Wk + l * DD, WkT, DMODEL, DMODEL);
      transpose_f2b<<<dim3(32, 32), 256, 0, stream>>>(Wv + l * DD, WvT, DMODEL, DMODEL);
      transpose_f2b<<<dim3(32, 32), 256, 0, stream>>>(Wo + l * DD, WoT, DMODEL, DMODEL);
      transpose_f2b<<<dim3(128, 32), 256, 0, stream>>>(W1 + l * DF, W1T, DMODEL, FDIM);
      transpose_f2b<<<dim3(32, 128), 256, 0, stream>>>(W2 + l * DF, W2T, FDIM, DMODEL);
      WkTl = WkT; WvTl = WvT; WoTl = WoT; W1Tl = W1T; W2Tl = W2T;
    }

    // merged qk-proj (z=0) + v-proj (z=1)
    gemm4w<false, true><<<dim3(DMODEL / 128, ROWS / 128, 2), 256, 0, stream>>>(
        xb, WkTl, bk + l * DMODEL, nullptr, qkb,
        yb, WvTl, bv + l * DMODEL, vb, ROWS, DMODEL, DMODEL);
    attn_kernel<<<dim3(SLEN / QBLK, BDIM * NHEAD), 256, 0, stream>>>(qkb, vb, ctxb);
    gemm4w<true, false><<<dim3(DMODEL / 128, ROWS / 128), 256, 0, stream>>>(
        ctxb, WoTl, bo + l * DMODEL, xb, tmpb,
        nullptr, nullptr, nullptr, nullptr, ROWS, DMODEL, DMODEL);
    ln_kernel<false><<<ROWS, 256, 0, stream>>>(tmpb, xb, ln1g + l * DMODEL, ln1b + l * DMODEL, nullptr);
    gemm8p<256, true, true><<<dim3(FDIM / 256, ROWS / 256), 512, 0, stream>>>(
        xb, W1Tl, b1 + l * FDIM, ffnb, ROWS, FDIM, DMODEL);
    gemm4w<true, false><<<dim3(DMODEL / 128, ROWS / 128), 256, 0, stream>>>(
        ffnb, W2Tl, b2 + l * DMODEL, xb, tmpb,
        nullptr, nullptr, nullptr, nullptr, ROWS, DMODEL, FDIM);
    if (l == NLAYER - 1) {
      ln_kernel<true><<<ROWS, 256, 0, stream>>>(tmpb, xb, ln2g + l * DMODEL, ln2b + l * DMODEL,
                                                (float4*)d_out);
    } else {
      ln_kernel<false><<<ROWS, 256, 0, stream>>>(tmpb, xb, ln2g + l * DMODEL, ln2b + l * DMODEL, nullptr);
    }
  }
}

// Round 18
// 1109.816 us; speedup vs baseline: 1.1103x; 1.1103x over previous
//
#include <hip/hip_runtime.h>
#include <stdint.h>

typedef unsigned short u16;
typedef __bf16 bf16x8 __attribute__((ext_vector_type(8)));
typedef float f32x4 __attribute__((ext_vector_type(4)));

#define BDIM 16
#define SLEN 512
#define DMODEL 1024
#define NHEAD 16
#define DHEAD 64
#define FDIM 4096
#define NLAYER 4
#define ROWS (BDIM*SLEN)   // 8192
#define KVT 64             // keys per attention tile
#define QBLK 128           // q-rows per attention block

// f32 -> bf16 round-to-nearest-even
__device__ __forceinline__ u16 f2b(float f) {
  uint32_t u = __builtin_bit_cast(uint32_t, f);
  u = (u + 0x7fffu + ((u >> 16) & 1u)) >> 16;
  return (u16)u;
}
__device__ __forceinline__ float b2f(u16 u) {
  return __builtin_bit_cast(float, (uint32_t)u << 16);
}
__device__ __forceinline__ float b2f_lo(uint32_t u) {
  return __builtin_bit_cast(float, u << 16);
}
__device__ __forceinline__ float b2f_hi(uint32_t u) {
  return __builtin_bit_cast(float, u & 0xffff0000u);
}

// async global->LDS, 16B per lane. LDS dest is WAVE-UNIFORM base (+lane*16 by HW);
// global src is per-lane (how we realize swizzled LDS layouts).
__device__ __forceinline__ void gl_lds16(const void* g, void* l) {
  uint32_t loff = (uint32_t)(uintptr_t)l;
  __builtin_amdgcn_global_load_lds(
      (__attribute__((address_space(1))) uint32_t*)(uintptr_t)g,
      (__attribute__((address_space(3))) uint32_t*)loff,
      16, 0, 0);
}

// ---------------- prep: xb = bf16(q + pe), yb = bf16(qa + pe) ----------------
__global__ __launch_bounds__(256) void prep_kernel(const float4* __restrict__ q,
                                                   const float4* __restrict__ qa,
                                                   const float4* __restrict__ pe,
                                                   u16* __restrict__ xb,
                                                   u16* __restrict__ yb) {
  int idx = blockIdx.x * 256 + threadIdx.x;
  int pidx = idx & (SLEN * DMODEL / 4 - 1);
  float4 qv = q[idx], av = qa[idx], pv = pe[pidx];
  uint32_t x0 = (uint32_t)f2b(qv.x + pv.x) | ((uint32_t)f2b(qv.y + pv.y) << 16);
  uint32_t x1 = (uint32_t)f2b(qv.z + pv.z) | ((uint32_t)f2b(qv.w + pv.w) << 16);
  uint32_t y0 = (uint32_t)f2b(av.x + pv.x) | ((uint32_t)f2b(av.y + pv.y) << 16);
  uint32_t y1 = (uint32_t)f2b(av.z + pv.z) | ((uint32_t)f2b(av.w + pv.w) << 16);
  ((uint2*)xb)[idx] = make_uint2(x0, x1);
  ((uint2*)yb)[idx] = make_uint2(y0, y1);
}

// ---------------- transpose f32 [M][N] -> bf16 [N][M], layer z ----------------
__global__ __launch_bounds__(256) void transpose_f2b(const float* __restrict__ in,
                                                     u16* __restrict__ out,
                                                     int M, int N) {
  __shared__ float t[32][33];
  int tx = threadIdx.x & 31, ty = threadIdx.x >> 5;
  int m0 = blockIdx.y * 32, n0 = blockIdx.x * 32;
  const float* inz = in + (size_t)blockIdx.z * M * N;
  u16* outz = out + (size_t)blockIdx.z * M * N;
  #pragma unroll
  for (int i = 0; i < 32; i += 8) t[ty + i][tx] = inz[(size_t)(m0 + ty + i) * N + n0 + tx];
  __syncthreads();
  #pragma unroll
  for (int i = 0; i < 32; i += 8) outz[(size_t)(n0 + ty + i) * M + m0 + tx] = f2b(t[tx][ty + i]);
}

// ---------------- 8-phase 256x256 GEMM (FFN1; proven config) ----------------
template<int BN, bool RELU, bool BF16OUT>
__global__ __launch_bounds__(512, 2) void gemm8p(const u16* __restrict__ Ap,
                                                 const u16* __restrict__ Bp,
                                                 const float* __restrict__ bias,
                                                 void* __restrict__ Cp,
                                                 int M, int N, int K) {
  constexpr int NBH = BN / 128;
  constexpr int NREP = BN / 64;
  constexpr int QN = NREP / 2;
  constexpr int HU = 8192;
  __shared__ __attribute__((aligned(16))) u16 lds[2][(2 + NBH) * HU];

  const int tid = threadIdx.x, wave = tid >> 6, lane = tid & 63;
  const int lg = lane >> 4, lc = lane & 15;
  const int wm = wave >> 2, wn = wave & 3;

  const int gx = gridDim.x;
  int nwg = gx * gridDim.y;
  int orig = blockIdx.y * gx + blockIdx.x;
  int qq = nwg >> 3, rr_ = nwg & 7;
  int xcd = orig & 7, ix = orig >> 3;
  int wg = (xcd < rr_ ? xcd * (qq + 1) : rr_ * (qq + 1) + (xcd - rr_) * qq) + ix;
  const int m0 = (wg / gx) * 256, n0 = (wg % gx) * BN;

  const int ldbyte = K * 2;
  const char* Ag = (const char*)Ap + (size_t)m0 * ldbyte;
  const char* Bg = (const char*)Bp + (size_t)n0 * ldbyte;

  int o1 = tid * 16, o2 = 8192 + tid * 16;
  int sr1 = o1 >> 7, sg1 = (((o1 >> 4) & 7) - sr1) & 7;
  int sr2 = o2 >> 7, sg2 = (((o2 >> 4) & 7) - sr2) & 7;
  const int soff1 = sr1 * ldbyte + sg1 * 16;
  const int soff2 = sr2 * ldbyte + sg2 * 16;
  const int NT = K >> 6;

  auto stageA = [&](int kt, int h, int buf) {
    const char* g = Ag + (size_t)h * 128 * ldbyte + (size_t)kt * 128;
    char* d = (char*)&lds[buf][h * HU] + wave * 1024;
    gl_lds16(g + soff1, d);
    gl_lds16(g + soff2, d + 8192);
  };
  auto stageB = [&](int kt, int h, int buf) {
    const char* g = Bg + (size_t)h * 128 * ldbyte + (size_t)kt * 128;
    char* d = (char*)&lds[buf][(2 + h) * HU] + wave * 1024;
    gl_lds16(g + soff1, d);
    gl_lds16(g + soff2, d + 8192);
  };

  const int bstart = wn * (BN / 4);
  const int bh = bstart >> 7, bc0 = bstart & 127;

  auto rdA = [&](const u16* base, int f, int kk) -> bf16x8 {
    int row = f * 16 + lc;
    return *(const bf16x8*)&base[row * 64 + (((kk * 4 + lg + row) & 7) << 3)];
  };
  auto rdB = [&](const u16* base, int jj, int kk) -> bf16x8 {
    int row = bc0 + jj * 16 + lc;
    return *(const bf16x8*)&base[row * 64 + (((kk * 4 + lg + row) & 7) << 3)];
  };

  f32x4 acc[8][NREP];
  #pragma unroll
  for (int f = 0; f < 8; f++)
    #pragma unroll
    for (int j = 0; j < NREP; j++) acc[f][j] = (f32x4){0.f, 0.f, 0.f, 0.f};

  stageA(0, 0, 0); stageA(0, 1, 0);
  stageB(0, 0, 0); if (NBH == 2) stageB(0, 1, 0);
  stageA(1, 0, 1); stageA(1, 1, 1);
  asm volatile("s_waitcnt vmcnt(4)\n\ts_barrier" ::: "memory");

  auto ktile = [&](int k, int buf) {
    const u16* Ab_ = &lds[buf][wm * HU];
    const u16* Bb_ = &lds[buf][(2 + bh) * HU];
    const int kn = (k + 1 < NT) ? k + 1 : NT - 1;
    const int k2 = (k + 2 < NT) ? k + 2 : NT - 1;
    bf16x8 a0[4][2], a1[4][2], b0[QN][2], b1[QN][2];

    #pragma unroll
    for (int f = 0; f < 4; f++) { a0[f][0] = rdA(Ab_, f, 0); a0[f][1] = rdA(Ab_, f, 1); }
    #pragma unroll
    for (int j = 0; j < QN; j++) { b0[j][0] = rdB(Bb_, j, 0); b0[j][1] = rdB(Bb_, j, 1); }
    stageB(kn, 0, buf ^ 1);
    asm volatile("s_barrier" ::: "memory");
    __builtin_amdgcn_s_setprio(1);
    #pragma unroll
    for (int f = 0; f < 4; f++)
      #pragma unroll
      for (int j = 0; j < QN; j++) {
        acc[f][j] = __builtin_amdgcn_mfma_f32_16x16x32_bf16(a0[f][0], b0[j][0], acc[f][j], 0, 0, 0);
        acc[f][j] = __builtin_amdgcn_mfma_f32_16x16x32_bf16(a0[f][1], b0[j][1], acc[f][j], 0, 0, 0);
      }
    __builtin_amdgcn_s_setprio(0);
    asm volatile("s_barrier" ::: "memory");

    #pragma unroll
    for (int f = 0; f < 4; f++) { a1[f][0] = rdA(Ab_, 4 + f, 0); a1[f][1] = rdA(Ab_, 4 + f, 1); }
    if (NBH == 2) stageB(kn, 1, buf ^ 1);
    asm volatile("s_barrier" ::: "memory");
    __builtin_amdgcn_s_setprio(1);
    #pragma unroll
    for (int f = 0; f < 4; f++)
      #pragma unroll
      for (int j = 0; j < QN; j++) {
        acc[4 + f][j] = __builtin_amdgcn_mfma_f32_16x16x32_bf16(a1[f][0], b0[j][0], acc[4 + f][j], 0, 0, 0);
        acc[4 + f][j] = __builtin_amdgcn_mfma_f32_16x16x32_bf16(a1[f][1], b0[j][1], acc[4 + f][j], 0, 0, 0);
      }
    __builtin_amdgcn_s_setprio(0);
    asm volatile("s_barrier" ::: "memory");

    #pragma unroll
    for (int j = 0; j < QN; j++) { b1[j][0] = rdB(Bb_, QN + j, 0); b1[j][1] = rdB(Bb_, QN + j, 1); }
    stageA(k2, 0, buf);
    asm volatile("s_barrier" ::: "memory");
    __builtin_amdgcn_s_setprio(1);
    #pragma unroll
    for (int f = 0; f < 4; f++)
      #pragma unroll
      for (int j = 0; j < QN; j++) {
        acc[4 + f][QN + j] = __builtin_amdgcn_mfma_f32_16x16x32_bf16(a1[f][0], b1[j][0], acc[4 + f][QN + j], 0, 0, 0);
        acc[4 + f][QN + j] = __builtin_amdgcn_mfma_f32_16x16x32_bf16(a1[f][1], b1[j][1], acc[4 + f][QN + j], 0, 0, 0);
      }
    __builtin_amdgcn_s_setprio(0);
    asm volatile("s_barrier" ::: "memory");

    stageA(k2, 1, buf);
    asm volatile("s_barrier" ::: "memory");
    __builtin_amdgcn_s_setprio(1);
    #pragma unroll
    for (int f = 0; f < 4; f++)
      #pragma unroll
      for (int j = 0; j < QN; j++) {
        acc[f][QN + j] = __builtin_amdgcn_mfma_f32_16x16x32_bf16(a0[f][0], b1[j][0], acc[f][QN + j], 0, 0, 0);
        acc[f][QN + j] = __builtin_amdgcn_mfma_f32_16x16x32_bf16(a0[f][1], b1[j][1], acc[f][QN + j], 0, 0, 0);
      }
    __builtin_amdgcn_s_setprio(0);
    asm volatile("s_waitcnt vmcnt(4)\n\ts_barrier" ::: "memory");
  };

  for (int k = 0; k < NT; k += 2) {
    ktile(k, 0);
    ktile(k + 1, 1);
  }

  #pragma unroll
  for (int f = 0; f < 8; f++) {
    int row = m0 + wm * 128 + f * 16 + lg * 4;
    #pragma unroll
    for (int j = 0; j < NREP; j++) {
      int col = n0 + bstart + j * 16 + lc;
      float bv = bias[col];
      #pragma unroll
      for (int t2 = 0; t2 < 4; t2++) {
        float v = acc[f][j][t2] + bv;
        if (RELU) v = fmaxf(v, 0.f);
        if (BF16OUT) ((u16*)Cp)[(size_t)(row + t2) * N + col] = f2b(v);
        else         ((float*)Cp)[(size_t)(row + t2) * N + col] = v;
      }
    }
  }
}

// ---------------- gemm4w v1 (round-16 proven): 128x128, BK=64, race-hardened, XCD swizzle ----------------
// DUAL: blockIdx.z==1 selects a second independent operand set (merged qk/v projections).
template<bool RESID, bool DUAL>
__global__ __launch_bounds__(256, 2) void gemm4w(const u16* __restrict__ Ap,
                                                 const u16* __restrict__ Bp,
                                                 const float* __restrict__ bias,
                                                 const u16* __restrict__ Rp,
                                                 u16* __restrict__ Cp,
                                                 const u16* __restrict__ Ap2,
                                                 const u16* __restrict__ Bp2,
                                                 const float* __restrict__ bias2,
                                                 u16* __restrict__ Cp2,
                                                 int M, int N, int K) {
  __shared__ __attribute__((aligned(16))) u16 As[2][128 * 64];
  __shared__ __attribute__((aligned(16))) u16 Bs[2][128 * 64];
  const int tid = threadIdx.x, wave = tid >> 6, lane = tid & 63;
  const int lg = lane >> 4, lc = lane & 15;
  const int wm = wave >> 1, wn = wave & 1;

  if (DUAL && blockIdx.z == 1) { Ap = Ap2; Bp = Bp2; bias = bias2; Cp = Cp2; }

  const int gx = gridDim.x;
  int nwg = gx * gridDim.y;
  int orig = blockIdx.y * gx + blockIdx.x;
  int qq = nwg >> 3, rr_ = nwg & 7;
  int xcd = orig & 7, ix = orig >> 3;
  int wg = (xcd < rr_ ? xcd * (qq + 1) : rr_ * (qq + 1) + (xcd - rr_) * qq) + ix;
  const int m0 = (wg / gx) * 128, n0 = (wg % gx) * 128;

  const int ldbyte = K * 2;
  const char* Ag = (const char*)Ap + (size_t)m0 * ldbyte;
  const char* Bg = (const char*)Bp + (size_t)n0 * ldbyte;
  const int NT = K >> 6;

  auto stage = [&](const char* gb, int kt, u16* lb) {
    #pragma unroll
    for (int c = 0; c < 4; c++) {
      int o = c * 4096 + tid * 16;
      int row = o >> 7;
      int g = (((o >> 4) & 7) - row) & 7;
      gl_lds16(gb + (size_t)row * ldbyte + (size_t)kt * 128 + g * 16,
               (char*)lb + c * 4096 + wave * 1024);
    }
  };
  auto rd = [&](const u16* base, int strip, int f, int kk) -> bf16x8 {
    int row = strip * 64 + f * 16 + lc;
    return *(const bf16x8*)&base[row * 64 + (((kk * 4 + lg + row) & 7) << 3)];
  };

  f32x4 acc[4][4];
  #pragma unroll
  for (int f = 0; f < 4; f++)
    #pragma unroll
    for (int n = 0; n < 4; n++) acc[f][n] = (f32x4){0.f, 0.f, 0.f, 0.f};

  stage(Ag, 0, As[0]); stage(Bg, 0, Bs[0]);
  stage(Ag, 1, As[1]); stage(Bg, 1, Bs[1]);
  asm volatile("s_waitcnt vmcnt(8)\n\ts_barrier" ::: "memory");

  for (int k = 0; k < NT; k++) {
    const int buf = k & 1;
    const int k2 = (k + 2 < NT) ? k + 2 : k;   // same-parity clamp: restage = identical bytes
    bf16x8 a[4][2], b[4][2];
    #pragma unroll
    for (int f = 0; f < 4; f++) { a[f][0] = rd(As[buf], wm, f, 0); a[f][1] = rd(As[buf], wm, f, 1); }
    #pragma unroll
    for (int n = 0; n < 4; n++) { b[n][0] = rd(Bs[buf], wn, n, 0); b[n][1] = rd(Bs[buf], wn, n, 1); }
    asm volatile("s_barrier" ::: "memory");              // B1
    __builtin_amdgcn_s_setprio(1);
    #pragma unroll
    for (int f = 0; f < 4; f++)
      #pragma unroll
      for (int n = 0; n < 2; n++) {
        acc[f][n] = __builtin_amdgcn_mfma_f32_16x16x32_bf16(a[f][0], b[n][0], acc[f][n], 0, 0, 0);
        acc[f][n] = __builtin_amdgcn_mfma_f32_16x16x32_bf16(a[f][1], b[n][1], acc[f][n], 0, 0, 0);
      }
    __builtin_amdgcn_s_setprio(0);
    asm volatile("s_waitcnt lgkmcnt(0)\n\ts_barrier" ::: "memory");  // B2: all LDS reads drained
    stage(Ag, k2, As[buf]);
    stage(Bg, k2, Bs[buf]);
    __builtin_amdgcn_s_setprio(1);
    #pragma unroll
    for (int f = 0; f < 4; f++)
      #pragma unroll
      for (int n = 2; n < 4; n++) {
        acc[f][n] = __builtin_amdgcn_mfma_f32_16x16x32_bf16(a[f][0], b[n][0], acc[f][n], 0, 0, 0);
        acc[f][n] = __builtin_amdgcn_mfma_f32_16x16x32_bf16(a[f][1], b[n][1], acc[f][n], 0, 0, 0);
      }
    __builtin_amdgcn_s_setprio(0);
    asm volatile("s_waitcnt vmcnt(8)\n\ts_barrier" ::: "memory");  // B3: tile k+1 landed
  }

  #pragma unroll
  for (int f = 0; f < 4; f++) {
    int row = m0 + wm * 64 + f * 16 + lg * 4;
    #pragma unroll
    for (int n = 0; n < 4; n++) {
      int col = n0 + wn * 64 + n * 16 + lc;
      float bv = bias[col];
      #pragma unroll
      for (int r = 0; r < 4; r++) {
        float v = acc[f][n][r] + bv;
        if (RESID) v += b2f(Rp[(size_t)(row + r) * N + col]);
        Cp[(size_t)(row + r) * N + col] = f2b(v);
      }
    }
  }
}

// ---------------- flash attention v7: QBLK=128, KVT=64, hardened sync, static-max softmax ----------------
__global__ __launch_bounds__(256, 2) void attn_kernel(const u16* __restrict__ QK,
                                                      const u16* __restrict__ V,
                                                      u16* __restrict__ CTX) {
  __shared__ __attribute__((aligned(16))) u16 Ks[2][KVT * 64];
  __shared__ __attribute__((aligned(16))) u16 VTs[64 * 72];
  __shared__ __attribute__((aligned(16))) u16 Ps[4][32 * 72];
  const int qt = blockIdx.x, bh = blockIdx.y;
  const int b = bh >> 4, h = bh & 15;
  const char* Qg = (const char*)(QK + (size_t)b * SLEN * DMODEL + h * DHEAD);
  const char* Vg = (const char*)(V + (size_t)b * SLEN * DMODEL + h * DHEAD);
  const int tid = threadIdx.x, wave = tid >> 6, lane = tid & 63;
  const int lg = lane >> 4, lc = lane & 15;
  const int ktmax = (qt * QBLK + QBLK - 2) >> 6;   // = 2*qt+1 (odd -> even iteration count)

  auto stageK = [&](int kt, int buf) {
    #pragma unroll
    for (int i = 0; i < 2; i++) {
      int o = i * 4096 + tid * 16;
      int row = o >> 7, slot = (o >> 4) & 7;
      int g = (slot - row) & 7;
      gl_lds16(Qg + (size_t)(kt * KVT + row) * (DMODEL * 2) + g * 16,
               (char*)Ks[buf] + i * 4096 + wave * 1024);
    }
  };
  const int vhi = lane >> 5, vls = lane & 31;
  const int vc_ = wave + 4 * vhi;
  auto loadV = [&](int kt, uint4 (&va)[2]) {
    const char* src = Vg + (size_t)(kt * KVT + 2 * vls) * (DMODEL * 2) + vc_ * 16;
    va[0] = *(const uint4*)src;
    va[1] = *(const uint4*)(src + DMODEL * 2);
  };
  auto writeVT = [&](const uint4 (&va)[2]) {
    u16 e0[8], e1[8];
    *(uint4*)e0 = va[0];
    *(uint4*)e1 = va[1];
    #pragma unroll
    for (int j = 0; j < 8; j++) {
      uint32_t pk = (uint32_t)e0[j] | ((uint32_t)e1[j] << 16);
      *(uint32_t*)&VTs[(8 * vc_ + j) * 72 + 2 * vls] = pk;
    }
  };

  uint4 vaA[2], vaB[2];
  bf16x8 aq[2][2];
  #pragma unroll
  for (int f = 0; f < 2; f++) {
    const int qrow = qt * QBLK + wave * 32 + f * 16 + lc;
    aq[f][0] = *(const bf16x8*)(Qg + (size_t)qrow * (DMODEL * 2) + lg * 16);
    aq[f][1] = *(const bf16x8*)(Qg + (size_t)qrow * (DMODEL * 2) + 64 + lg * 16);
  }
  stageK(0, 0);
  loadV(0, vaA);
  stageK(1, 1);
  asm volatile("s_waitcnt vmcnt(2)\n\ts_barrier" ::: "memory");

  float l_run[2][4] = {{0.f, 0.f, 0.f, 0.f}, {0.f, 0.f, 0.f, 0.f}};
  f32x4 acc_o[2][4];
  #pragma unroll
  for (int f = 0; f < 2; f++)
    #pragma unroll
    for (int n = 0; n < 4; n++) acc_o[f][n] = (f32x4){0.f, 0.f, 0.f, 0.f};

  auto iter = [&](int kt, int cur, uint4 (&vc)[2], uint4 (&vn)[2]) {
    const int kn = (kt + 1 <= ktmax) ? kt + 1 : ktmax;
    const int k2 = (kt + 2 <= ktmax) ? kt + 2 : kt;   // same-parity clamp (identical bytes)

    asm volatile("s_waitcnt vmcnt(2) lgkmcnt(0)" ::: "memory");
    __builtin_amdgcn_s_barrier();                     // B0: VT free for rewrite
    writeVT(vc);
    loadV(kn, vn);

    f32x4 sc[2][4];
    #pragma unroll
    for (int f = 0; f < 2; f++)
      #pragma unroll
      for (int n = 0; n < 4; n++) sc[f][n] = (f32x4){0.f, 0.f, 0.f, 0.f};
    #pragma unroll
    for (int n = 0; n < 4; n++) {
      int row = n * 16 + lc;
      bf16x8 bk0 = *(const bf16x8*)&Ks[cur][row * 64 + (((lg + row) & 7) << 3)];
      bf16x8 bk1 = *(const bf16x8*)&Ks[cur][row * 64 + (((4 + lg + row) & 7) << 3)];
      #pragma unroll
      for (int f = 0; f < 2; f++) {
        sc[f][n] = __builtin_amdgcn_mfma_f32_16x16x32_bf16(aq[f][0], bk0, sc[f][n], 0, 0, 0);
        sc[f][n] = __builtin_amdgcn_mfma_f32_16x16x32_bf16(aq[f][1], bk1, sc[f][n], 0, 0, 0);
      }
    }

    #pragma unroll
    for (int f = 0; f < 2; f++) {
      const int qbase = qt * QBLK + wave * 32 + f * 16 + lg * 4;
      #pragma unroll
      for (int n = 0; n < 4; n++) {
        int kg = kt * KVT + n * 16 + lc;
        #pragma unroll
        for (int r = 0; r < 4; r++) {
          float e = __expf(fmaf(sc[f][n][r], 0.125f, -24.f));
          float p = (kg < qbase + r) ? e : 0.f;
          l_run[f][r] += p;
          Ps[wave][(f * 16 + lg * 4 + r) * 72 + n * 16 + lc] = f2b(p);
        }
      }
    }

    asm volatile("s_waitcnt lgkmcnt(0)" ::: "memory");
    __builtin_amdgcn_s_barrier();            // B1: VT+P visible; QK reads of Ks[cur] done
    stageK(k2, cur);

    bf16x8 ap[2][2];
    #pragma unroll
    for (int f = 0; f < 2; f++) {
      ap[f][0] = *(const bf16x8*)&Ps[wave][(f * 16 + lc) * 72 + lg * 8];
      ap[f][1] = *(const bf16x8*)&Ps[wave][(f * 16 + lc) * 72 + 32 + lg * 8];
    }
    #pragma unroll
    for (int n2 = 0; n2 < 4; n2++) {
      bf16x8 bv0 = *(const bf16x8*)&VTs[(n2 * 16 + lc) * 72 + lg * 8];
      bf16x8 bv1 = *(const bf16x8*)&VTs[(n2 * 16 + lc) * 72 + 32 + lg * 8];
      #pragma unroll
      for (int f = 0; f < 2; f++) {
        acc_o[f][n2] = __builtin_amdgcn_mfma_f32_16x16x32_bf16(ap[f][0], bv0, acc_o[f][n2], 0, 0, 0);
        acc_o[f][n2] = __builtin_amdgcn_mfma_f32_16x16x32_bf16(ap[f][1], bv1, acc_o[f][n2], 0, 0, 0);
      }
    }
  };

  for (int kt = 0; kt <= ktmax; kt += 2) {
    iter(kt, 0, vaA, vaB);
    iter(kt + 1, 1, vaB, vaA);   // ktmax odd -> always valid
  }

  #pragma unroll
  for (int d = 1; d < 16; d <<= 1)
    #pragma unroll
    for (int f = 0; f < 2; f++)
      #pragma unroll
      for (int r = 0; r < 4; r++) l_run[f][r] += __shfl_xor(l_run[f][r], d, 64);

  asm volatile("s_waitcnt vmcnt(0)" ::: "memory");
  #pragma unroll
  for (int f = 0; f < 2; f++)
    #pragma unroll
    for (int n2 = 0; n2 < 4; n2++)
      #pragma unroll
      for (int r = 0; r < 4; r++) {
        int sq = qt * QBLK + wave * 32 + f * 16 + lg * 4 + r;
        float v = (sq == 0) ? 0.f : acc_o[f][n2][r] / l_run[f][r];
        CTX[((size_t)b * SLEN + sq) * DMODEL + h * DHEAD + n2 * 16 + lc] = f2b(v);
      }
}

// ---------------- pure row LayerNorm (bit-exact); OUT32 fuses the f32 expand ----------------
template<bool OUT32>
__global__ __launch_bounds__(256) void ln_kernel(const u16* __restrict__ tmp,
                                                 u16* __restrict__ xb,
                                                 const float* __restrict__ gw,
                                                 const float* __restrict__ bw,
                                                 float4* __restrict__ outf) {
  __shared__ float red[4], red2[4];
  const int row = blockIdx.x, t = threadIdx.x;
  const size_t base = (size_t)row * DMODEL + t * 4;
  uint2 tv = *(const uint2*)&tmp[base];
  float v[4];
  v[0] = b2f_lo(tv.x); v[1] = b2f_hi(tv.x);
  v[2] = b2f_lo(tv.y); v[3] = b2f_hi(tv.y);
  float s = v[0] + v[1] + v[2] + v[3];
  #pragma unroll
  for (int d = 1; d < 64; d <<= 1) s += __shfl_xor(s, d, 64);
  if ((t & 63) == 0) red[t >> 6] = s;
  __syncthreads();
  float mean = (red[0] + red[1] + red[2] + red[3]) * (1.f / DMODEL);
  float q2 = 0.f;
  #pragma unroll
  for (int i = 0; i < 4; i++) { float d_ = v[i] - mean; q2 += d_ * d_; }
  #pragma unroll
  for (int d = 1; d < 64; d <<= 1) q2 += __shfl_xor(q2, d, 64);
  if ((t & 63) == 0) red2[t >> 6] = q2;
  __syncthreads();
  float var = (red2[0] + red2[1] + red2[2] + red2[3]) * (1.f / DMODEL);
  float rs = rsqrtf(var + 1e-5f);
  float4 gv = *(const float4*)&gw[t * 4];
  float4 bv4 = *(const float4*)&bw[t * 4];
  float o0 = (v[0] - mean) * rs * gv.x + bv4.x;
  float o1 = (v[1] - mean) * rs * gv.y + bv4.y;
  float o2 = (v[2] - mean) * rs * gv.z + bv4.z;
  float o3 = (v[3] - mean) * rs * gv.w + bv4.w;
  if (OUT32) {
    outf[(size_t)row * (DMODEL / 4) + t] =
        make_float4(b2f(f2b(o0)), b2f(f2b(o1)), b2f(f2b(o2)), b2f(f2b(o3)));
  } else {
    uint2 pk;
    pk.x = (uint32_t)f2b(o0) | ((uint32_t)f2b(o1) << 16);
    pk.y = (uint32_t)f2b(o2) | ((uint32_t)f2b(o3) << 16);
    *(uint2*)&xb[base] = pk;
  }
}

extern "C" void kernel_launch(void* const* d_in, const int* in_sizes, int n_in,
                              void* d_out, int out_size, void* d_ws, size_t ws_size,
                              hipStream_t stream) {
  (void)in_sizes; (void)n_in; (void)out_size;
  const float* q    = (const float*)d_in[0];
  const float* qa   = (const float*)d_in[1];
  const float* pe   = (const float*)d_in[2];
  const float* Wk   = (const float*)d_in[3];
  const float* bk   = (const float*)d_in[4];
  const float* Wv   = (const float*)d_in[5];
  const float* bv   = (const float*)d_in[6];
  const float* Wo   = (const float*)d_in[7];
  const float* bo   = (const float*)d_in[8];
  const float* ln1g = (const float*)d_in[9];
  const float* ln1b = (const float*)d_in[10];
  const float* W1   = (const float*)d_in[11];
  const float* b1   = (const float*)d_in[12];
  const float* W2   = (const float*)d_in[13];
  const float* b2   = (const float*)d_in[14];
  const float* ln2g = (const float*)d_in[15];
  const float* ln2b = (const float*)d_in[16];

  char* w = (char*)d_ws;
  u16* xb   = (u16*)w; w += (size_t)ROWS * DMODEL * 2;
  u16* yb   = (u16*)w; w += (size_t)ROWS * DMODEL * 2;
  u16* qkb  = (u16*)w; w += (size_t)ROWS * DMODEL * 2;
  u16* vb   = (u16*)w; w += (size_t)ROWS * DMODEL * 2;
  u16* ctxb = (u16*)w; w += (size_t)ROWS * DMODEL * 2;
  u16* ffnb = (u16*)w; w += (size_t)ROWS * FDIM * 2;
  u16* tmpb = qkb;   // alias: qkb dead when tmpb written

  const size_t DD = (size_t)DMODEL * DMODEL, DF = (size_t)DMODEL * FDIM;
  size_t used = (size_t)(w - (char*)d_ws);
  const bool hoist = ws_size >= used + (3 * DD + 2 * DF) * NLAYER * 2;

  u16 *WkT, *WvT, *WoT, *W1T, *W2T;
  if (hoist) {
    WkT = (u16*)w; w += DD * NLAYER * 2;
    WvT = (u16*)w; w += DD * NLAYER * 2;
    WoT = (u16*)w; w += DD * NLAYER * 2;
    W1T = (u16*)w; w += DF * NLAYER * 2;
    W2T = (u16*)w; w += DF * NLAYER * 2;
  } else {
    WkT = (u16*)w; w += DD * 2;
    WvT = (u16*)w; w += DD * 2;
    WoT = (u16*)w; w += DD * 2;
    W1T = (u16*)w; w += DF * 2;
    W2T = (u16*)w; w += DF * 2;
  }

  prep_kernel<<<ROWS * DMODEL / 4 / 256, 256, 0, stream>>>(
      (const float4*)q, (const float4*)qa, (const float4*)pe, xb, yb);

  if (hoist) {
    transpose_f2b<<<dim3(32, 32, NLAYER), 256, 0, stream>>>(Wk, WkT, DMODEL, DMODEL);
    transpose_f2b<<<dim3(32, 32, NLAYER), 256, 0, stream>>>(Wv, WvT, DMODEL, DMODEL);
    transpose_f2b<<<dim3(32, 32, NLAYER), 256, 0, stream>>>(Wo, WoT, DMODEL, DMODEL);
    transpose_f2b<<<dim3(128, 32, NLAYER), 256, 0, stream>>>(W1, W1T, DMODEL, FDIM);
    transpose_f2b<<<dim3(32, 128, NLAYER), 256, 0, stream>>>(W2, W2T, FDIM, DMODEL);
  }

  for (int l = 0; l < NLAYER; l++) {
    u16 *WkTl, *WvTl, *WoTl, *W1Tl, *W2Tl;
    if (hoist) {
      WkTl = WkT + l * DD; WvTl = WvT + l * DD; WoTl = WoT + l * DD;
      W1Tl = W1T + l * DF; W2Tl = W2T + l * DF;
    } else {
      transpose_f2b<<<dim3(32, 32), 256, 0, stream>>>(Wk + l * DD, WkT, DMODEL, DMODEL);
      transpose_f2b<<<dim3(32, 32), 256, 0, stream>>>(Wv + l * DD, WvT, DMODEL, DMODEL);
      transpose_f2b<<<dim3(32, 32), 256, 0, stream>>>(Wo + l * DD, WoT, DMODEL, DMODEL);
      transpose_f2b<<<dim3(128, 32), 256, 0, stream>>>(W1 + l * DF, W1T, DMODEL, FDIM);
      transpose_f2b<<<dim3(32, 128), 256, 0, stream>>>(W2 + l * DF, W2T, FDIM, DMODEL);
      WkTl = WkT; WvTl = WvT; WoTl = WoT; W1Tl = W1T; W2Tl = W2T;
    }

    // merged qk-proj (z=0) + v-proj (z=1)
    gemm4w<false, true><<<dim3(DMODEL / 128, ROWS / 128, 2), 256, 0, stream>>>(
        xb, WkTl, bk + l * DMODEL, nullptr, qkb,
        yb, WvTl, bv + l * DMODEL, vb, ROWS, DMODEL, DMODEL);
    attn_kernel<<<dim3(SLEN / QBLK, BDIM * NHEAD), 256, 0, stream>>>(qkb, vb, ctxb);
    gemm4w<true, false><<<dim3(DMODEL / 128, ROWS / 128), 256, 0, stream>>>(
        ctxb, WoTl, bo + l * DMODEL, xb, tmpb,
        nullptr, nullptr, nullptr, nullptr, ROWS, DMODEL, DMODEL);
    ln_kernel<false><<<ROWS, 256, 0, stream>>>(tmpb, xb, ln1g + l * DMODEL, ln1b + l * DMODEL, nullptr);
    gemm8p<256, true, true><<<dim3(FDIM / 256, ROWS / 256), 512, 0, stream>>>(
        xb, W1Tl, b1 + l * FDIM, ffnb, ROWS, FDIM, DMODEL);
    gemm4w<true, false><<<dim3(DMODEL / 128, ROWS / 128), 256, 0, stream>>>(
        ffnb, W2Tl, b2 + l * DMODEL, xb, tmpb,
        nullptr, nullptr, nullptr, nullptr, ROWS, DMODEL, FDIM);
    if (l == NLAYER - 1) {
      ln_kernel<true><<<ROWS, 256, 0, stream>>>(tmpb, xb, ln2g + l * DMODEL, ln2b + l * DMODEL,
                                                (float4*)d_out);
    } else {
      ln_kernel<false><<<ROWS, 256, 0, stream>>>(tmpb, xb, ln2g + l * DMODEL, ln2b + l * DMODEL, nullptr);
    }
  }
}